// Round 6
// baseline (144.220 us; speedup 1.0000x reference)
//
#include <hip/hip_runtime.h>
#include <math.h>

#define N_COLS 1024
#define NRINGS 8

// ---- geometry: 64 lanes/row (full wave), 16 cols/thread, 4 rows/thread ----
#define TPR    64
#define CHUNK  16
#define QUADS_PER_BLOCK 4         // 256 threads / 64 lanes -> 4 quads -> 16 rows/block

// ws layout (floats) — identical to the R6/R8/R9-proven layout
#define F_OFF    16384            // CS  : 8 rings * 512 float4 = 16384 floats (64 KB)
#define A_OFF    24576            // F   : 8 rings * 256 float4 =  8192 floats (32 KB)
#define AUX_OFF  25088            // A   : 8 rings * 64 floats  =   512 floats
#define WS_FLOATS 25104           // AUX : 8 float2             =    16 floats

// =====================  setup: build angle tables  ======================
// grid = 32 blocks (4 per ring, 256 angles each). 1 sincos per thread.
//   CS  [(r*8 + jp)*64 + t] : float4 (c_j0,s_j0,c_j1,s_j1), k = t*16 + 2*jp
//   F   [(r*4 + q )*64 + t] : float4 f_j = c_j * prod_{l>j in chunk}(-s_l)
//   A   [r*64 + t]          : prod_j(-s_j) over chunk t
//   AUX [r]                 : real (c,s) at k=1023 (table entry doctored to
//                             (0,-1) = exact no-op chain step)
__global__ __launch_bounds__(256)
void ced_setup(const float* __restrict__ ae,
               const float* __restrict__ ad,
               float* __restrict__ ws)
{
    __shared__ float2 ls[256];
    const int r   = blockIdx.x >> 2;
    const int b   = blockIdx.x & 3;
    const int tid = threadIdx.x;
    const int k   = (b << 8) + tid;           // t = k>>4, j = k&15
    const float* ang = (r < 4) ? (ae + (r << 10)) : (ad + ((r - 4) << 10));

    float sv, cv;
    sincosf(ang[k], &sv, &cv);
    if (k == N_COLS - 1) {
        ((float2*)(ws + AUX_OFF))[r] = make_float2(cv, sv);
        cv = 0.f; sv = -1.f;                  // doctored: no-op step
    }
    ls[tid] = make_float2(cv, sv);
    __syncthreads();

    if (!(tid & 1)) {                         // paired (c,s) table
        float2 e0 = ls[tid], e1 = ls[tid + 1];
        int t  = k >> 4;
        int jp = (k & 15) >> 1;
        ((float4*)ws)[(r*8 + jp)*64 + t] = make_float4(e0.x, e0.y, e1.x, e1.y);
    }

    if (tid < 64) {                           // F and A via 2-round shfl product-scan
        const int lt = tid >> 2;              // local chunk 0..15
        const int q  = tid & 3;               // 4-element sub-segment 0..3
        const int t  = (b << 4) + lt;         // global chunk 0..63
        const int j0 = lt * CHUNK + 4 * q;
        float2 e0 = ls[j0], e1 = ls[j0+1], e2 = ls[j0+2], e3 = ls[j0+3];

        float f3 = e3.x;       float P = -e3.y;
        float f2 = e2.x * P;   P *= -e2.y;
        float f1 = e1.x * P;   P *= -e1.y;
        float f0 = e0.x * P;   P *= -e0.y;

        float ip = P;                         // inclusive suffix product over segments
        #pragma unroll
        for (int d = 1; d < 4; d <<= 1) {
            float tmp = __shfl_down(ip, d);
            if (q + d < 4) ip *= tmp;
        }
        float ex = __shfl_down(ip, 1);
        if (q == 3) ex = 1.f;
        f0 *= ex; f1 *= ex; f2 *= ex; f3 *= ex;

        ((float4*)(ws + F_OFF))[(r*4 + q)*64 + t] = make_float4(f0, f1, f2, f3);
        if (q == 0) ws[A_OFF + r*TPR + t] = ip;
    }
}

// =====================  main: fused enc->blend->dec  ====================
// R9 post-mortem: 2 rows/thread beat 1 row (44 vs 54 us) despite HALF the
// waves -> per-wave per-ring FIXED costs (table loads, 6-round scan,
// y0/yN/up shuffles) dominate; amortize them. Also VGPR=60 left the
// register file ~70% idle while the grid capped residency.
// R10: 4 rows/thread + register-double-buffered ring tables. Grid 512
// blocks = 2 waves/SIMD, where the VGPR ladder allows 256 regs free of
// occupancy cost -> spend ~96 VGPR on csR/fvR[2] and issue ring r+1's 12
// table loads at the top of ring r (a full ring of compute hides them).
// Ring loop fully unrolled so all double-buffer indices are compile-time.
__global__ __launch_bounds__(256, 2)
void ced_main(const float* __restrict__ x,
              const float* __restrict__ ws,
              const float* __restrict__ hw,
              const float* __restrict__ hs,
              float* __restrict__ out, int B)
{
    const int tid  = threadIdx.x;
    const int t    = tid & 63;                       // chunk index within row
    const int quad = blockIdx.x * QUADS_PER_BLOCK + (tid >> 6);
    const size_t rowA = (size_t)(4 * quad) * N_COLS;
    const size_t rowB = rowA + N_COLS;
    const size_t rowC = rowB + N_COLS;
    const size_t rowD = rowC + N_COLS;

    const float4* CSg  = (const float4*)ws;
    const float4* Fg   = (const float4*)(ws + F_OFF);
    const float*  Ag   = ws + A_OFF;
    const float2* AUXg = (const float2*)(ws + AUX_OFF);

    // ---- prefetch ring 0 tables into registers (buf 0) ----
    float4 csR[2][8];
    float4 fvR[2][4];
    #pragma unroll
    for (int jp = 0; jp < 8; ++jp) csR[0][jp] = CSg[jp * 64 + t];
    #pragma unroll
    for (int qi = 0; qi < 4; ++qi) fvR[0][qi] = Fg[qi * 64 + t];

    // ---- load x (4 rows, 16 cols each) ----
    float ya[CHUNK], yb[CHUNK], yc[CHUNK], yd[CHUNK];
    {
        const float4* xa = (const float4*)(x + rowA + t * CHUNK);
        const float4* xb = (const float4*)(x + rowB + t * CHUNK);
        const float4* xc = (const float4*)(x + rowC + t * CHUNK);
        const float4* xd = (const float4*)(x + rowD + t * CHUNK);
        #pragma unroll
        for (int i = 0; i < 4; ++i) {
            float4 va = xa[i], vb = xb[i], vc = xc[i], vd = xd[i];
            ya[4*i] = va.x; ya[4*i+1] = va.y; ya[4*i+2] = va.z; ya[4*i+3] = va.w;
            yb[4*i] = vb.x; yb[4*i+1] = vb.y; yb[4*i+2] = vb.z; yb[4*i+3] = vb.w;
            yc[4*i] = vc.x; yc[4*i+1] = vc.y; yc[4*i+2] = vc.z; yc[4*i+3] = vc.w;
            yd[4*i] = vd.x; yd[4*i+1] = vd.y; yd[4*i+2] = vd.z; yd[4*i+3] = vd.w;
        }
    }

    const float w   = 1.f / (1.f + expf(-hw[0]));
    const float omw = 1.f - w;

    #pragma unroll
    for (int r = 0; r < NRINGS; ++r) {
        const int cb = r & 1;                        // compile-time after unroll
        const int nb = cb ^ 1;

        // ---- issue ring r+1's table loads (covered by this ring's compute) ----
        if (r < NRINGS - 1) {
            #pragma unroll
            for (int jp = 0; jp < 8; ++jp)
                csR[nb][jp] = CSg[(r + 1) * 512 + jp * 64 + t];
            #pragma unroll
            for (int qi = 0; qi < 4; ++qi)
                fvR[nb][qi] = Fg[(r + 1) * 256 + qi * 64 + t];
        }

        const float  saI = Ag[r * TPR + t];
        const float2 cN  = AUXg[r];                  // uniform -> scalar load

        if (r == 4) {                 // bottleneck blend + output 0
            float4* oa = (float4*)(out + rowA + t * CHUNK);
            float4* ob = (float4*)(out + rowB + t * CHUNK);
            float4* oc = (float4*)(out + rowC + t * CHUNK);
            float4* od = (float4*)(out + rowD + t * CHUNK);
            const float4* hp = (const float4*)(hs + t * CHUNK);
            #pragma unroll
            for (int i = 0; i < 4; ++i) {
                float4 h = hp[i];
                float4 na, nb2, nc, nd;
                na.x  = fmaf(omw, ya[4*i+0], w * h.x);
                na.y  = fmaf(omw, ya[4*i+1], w * h.y);
                na.z  = fmaf(omw, ya[4*i+2], w * h.z);
                na.w  = fmaf(omw, ya[4*i+3], w * h.w);
                nb2.x = fmaf(omw, yb[4*i+0], w * h.x);
                nb2.y = fmaf(omw, yb[4*i+1], w * h.y);
                nb2.z = fmaf(omw, yb[4*i+2], w * h.z);
                nb2.w = fmaf(omw, yb[4*i+3], w * h.w);
                nc.x  = fmaf(omw, yc[4*i+0], w * h.x);
                nc.y  = fmaf(omw, yc[4*i+1], w * h.y);
                nc.z  = fmaf(omw, yc[4*i+2], w * h.z);
                nc.w  = fmaf(omw, yc[4*i+3], w * h.w);
                nd.x  = fmaf(omw, yd[4*i+0], w * h.x);
                nd.y  = fmaf(omw, yd[4*i+1], w * h.y);
                nd.z  = fmaf(omw, yd[4*i+2], w * h.z);
                nd.w  = fmaf(omw, yd[4*i+3], w * h.w);
                oa[i] = na; ob[i] = nb2; oc[i] = nc; od[i] = nd;
                ya[4*i+0] = na.x;  ya[4*i+1] = na.y;  ya[4*i+2] = na.z;  ya[4*i+3] = na.w;
                yb[4*i+0] = nb2.x; yb[4*i+1] = nb2.y; yb[4*i+2] = nb2.z; yb[4*i+3] = nb2.w;
                yc[4*i+0] = nc.x;  yc[4*i+1] = nc.y;  yc[4*i+2] = nc.z;  yc[4*i+3] = nc.w;
                yd[4*i+0] = nd.x;  yd[4*i+1] = nd.y;  yd[4*i+2] = nd.z;  yd[4*i+3] = nd.w;
            }
        }

        float y0a = __shfl(ya[0],       0);
        float yNa = __shfl(ya[CHUNK-1], 63);
        float y0b = __shfl(yb[0],       0);
        float yNb = __shfl(yb[CHUNK-1], 63);
        float y0c = __shfl(yc[0],       0);
        float yNc = __shfl(yc[CHUNK-1], 63);
        float y0d = __shfl(yd[0],       0);
        float yNd = __shfl(yd[CHUNK-1], 63);
        float CinitA = cN.x * yNa - cN.y * y0a;
        float CinitB = cN.x * yNb - cN.y * y0b;
        float CinitC = cN.x * yNc - cN.y * y0c;
        float CinitD = cN.x * yNd - cN.y * y0d;
        float x0nA   = fmaf(cN.y, yNa, cN.x * y0a);
        float x0nB   = fmaf(cN.y, yNb, cN.x * y0b);
        float x0nC   = fmaf(cN.y, yNc, cN.x * y0c);
        float x0nD   = fmaf(cN.y, yNd, cN.x * y0d);
        if (t == 0) { ya[0] = x0nA; yb[0] = x0nB; yc[0] = x0nC; yd[0] = x0nD; }

        // ---- pass 1: four independent local chains (carry_in = 0) ----
        float carA = 0.f, carB = 0.f, carC = 0.f, carD = 0.f;
        float ztA = 0.f, ztB = 0.f, ztC = 0.f, ztD = 0.f;
        #pragma unroll
        for (int jp = CHUNK/2 - 1; jp >= 0; --jp) {
            float4 cs4 = csR[cb][jp];                // (c_j0,s_j0,c_j1,s_j1)
            const int j1 = 2*jp + 1;
            float z1a = fmaf(cs4.w, ya[j1], cs4.z * carA);
            float z1b = fmaf(cs4.w, yb[j1], cs4.z * carB);
            float z1c = fmaf(cs4.w, yc[j1], cs4.z * carC);
            float z1d = fmaf(cs4.w, yd[j1], cs4.z * carD);
            carA = fmaf(-cs4.w, carA, cs4.z * ya[j1]);
            carB = fmaf(-cs4.w, carB, cs4.z * yb[j1]);
            carC = fmaf(-cs4.w, carC, cs4.z * yc[j1]);
            carD = fmaf(-cs4.w, carD, cs4.z * yd[j1]);
            if (j1 == CHUNK - 1) { ztA = z1a; ztB = z1b; ztC = z1c; ztD = z1d; }
            else                 { ya[j1+1] = z1a; yb[j1+1] = z1b;
                                   yc[j1+1] = z1c; yd[j1+1] = z1d; }
            const int j0 = 2*jp;
            float z0a = fmaf(cs4.y, ya[j0], cs4.x * carA);
            float z0b = fmaf(cs4.y, yb[j0], cs4.x * carB);
            float z0c = fmaf(cs4.y, yc[j0], cs4.x * carC);
            float z0d = fmaf(cs4.y, yd[j0], cs4.x * carD);
            carA = fmaf(-cs4.y, carA, cs4.x * ya[j0]);
            carB = fmaf(-cs4.y, carB, cs4.x * yb[j0]);
            carC = fmaf(-cs4.y, carC, cs4.x * yc[j0]);
            carD = fmaf(-cs4.y, carD, cs4.x * yd[j0]);
            ya[j0+1] = z0a; yb[j0+1] = z0b; yc[j0+1] = z0c; yd[j0+1] = z0d;
        }

        // ---- affine suffix scan over 64 lanes (sa shared across 4 rows) ----
        float sa = saI, sbA = carA, sbB = carB, sbC = carC, sbD = carD;
        #pragma unroll
        for (int d = 1; d < TPR; d <<= 1) {
            float a2  = __shfl_down(sa,  d);
            float b2a = __shfl_down(sbA, d);
            float b2b = __shfl_down(sbB, d);
            float b2c = __shfl_down(sbC, d);
            float b2d = __shfl_down(sbD, d);
            if (t + d < TPR) {
                sbA = fmaf(sa, b2a, sbA);
                sbB = fmaf(sa, b2b, sbB);
                sbC = fmaf(sa, b2c, sbC);
                sbD = fmaf(sa, b2d, sbD);
                sa *= a2;
            }
        }
        float ea  = __shfl_down(sa,  1);
        float ebA = __shfl_down(sbA, 1);
        float ebB = __shfl_down(sbB, 1);
        float ebC = __shfl_down(sbC, 1);
        float ebD = __shfl_down(sbD, 1);
        float zfA = fmaf(sa, CinitA, sbA);           // lane0: final z[0]
        float zfB = fmaf(sa, CinitB, sbB);
        float zfC = fmaf(sa, CinitC, sbC);
        float zfD = fmaf(sa, CinitD, sbD);
        float CinA = (t == TPR - 1) ? CinitA : fmaf(ea, CinitA, ebA);
        float CinB = (t == TPR - 1) ? CinitB : fmaf(ea, CinitB, ebB);
        float CinC = (t == TPR - 1) ? CinitC : fmaf(ea, CinitC, ebC);
        float CinD = (t == TPR - 1) ? CinitD : fmaf(ea, CinitD, ebD);

        // ---- pass 2: independent fix-up with precomputed f ----
        #pragma unroll
        for (int qi = CHUNK/4 - 1; qi >= 0; --qi) {
            float4 f4 = fvR[cb][qi];
            const int j = 4*qi;
            if (j + 3 == CHUNK - 1) {
                ztA = fmaf(f4.w, CinA, ztA); ztB = fmaf(f4.w, CinB, ztB);
                ztC = fmaf(f4.w, CinC, ztC); ztD = fmaf(f4.w, CinD, ztD);
            } else {
                ya[j+4] = fmaf(f4.w, CinA, ya[j+4]); yb[j+4] = fmaf(f4.w, CinB, yb[j+4]);
                yc[j+4] = fmaf(f4.w, CinC, yc[j+4]); yd[j+4] = fmaf(f4.w, CinD, yd[j+4]);
            }
            ya[j+3] = fmaf(f4.z, CinA, ya[j+3]);  yb[j+3] = fmaf(f4.z, CinB, yb[j+3]);
            yc[j+3] = fmaf(f4.z, CinC, yc[j+3]);  yd[j+3] = fmaf(f4.z, CinD, yd[j+3]);
            ya[j+2] = fmaf(f4.y, CinA, ya[j+2]);  yb[j+2] = fmaf(f4.y, CinB, yb[j+2]);
            yc[j+2] = fmaf(f4.y, CinC, yc[j+2]);  yd[j+2] = fmaf(f4.y, CinD, yd[j+2]);
            ya[j+1] = fmaf(f4.x, CinA, ya[j+1]);  yb[j+1] = fmaf(f4.x, CinB, yb[j+1]);
            yc[j+1] = fmaf(f4.x, CinC, yc[j+1]);  yd[j+1] = fmaf(f4.x, CinD, yd[j+1]);
        }

        float upA = __shfl_up(ztA, 1);               // lane t-1's top -> slot 16t
        float upB = __shfl_up(ztB, 1);
        float upC = __shfl_up(ztC, 1);
        float upD = __shfl_up(ztD, 1);
        ya[0] = (t == 0) ? zfA : upA;
        yb[0] = (t == 0) ? zfB : upB;
        yc[0] = (t == 0) ? zfC : upC;
        yd[0] = (t == 0) ? zfD : upD;
    }

    float4* oa = (float4*)(out + (size_t)B * N_COLS + rowA + t * CHUNK);
    float4* ob = (float4*)(out + (size_t)B * N_COLS + rowB + t * CHUNK);
    float4* oc = (float4*)(out + (size_t)B * N_COLS + rowC + t * CHUNK);
    float4* od = (float4*)(out + (size_t)B * N_COLS + rowD + t * CHUNK);
    #pragma unroll
    for (int i = 0; i < 4; ++i) {
        oa[i] = make_float4(ya[4*i], ya[4*i+1], ya[4*i+2], ya[4*i+3]);
        ob[i] = make_float4(yb[4*i], yb[4*i+1], yb[4*i+2], yb[4*i+3]);
        oc[i] = make_float4(yc[4*i], yc[4*i+1], yc[4*i+2], yc[4*i+3]);
        od[i] = make_float4(yd[4*i], yd[4*i+1], yd[4*i+2], yd[4*i+3]);
    }
}

// ==================  fallback (self-contained, ws-free)  =================
__global__ __launch_bounds__(256, 2)
void ced_fallback(const float* __restrict__ x,
                  const float* __restrict__ ae,
                  const float* __restrict__ ad,
                  const float* __restrict__ hw,
                  const float* __restrict__ hs,
                  float* __restrict__ out, int B)
{
    __shared__ float2 s_cs[NRINGS * 64 * 16];
    __shared__ float  s_A [NRINGS * 16];
    __shared__ float2 s_aux[NRINGS];

    const int tid = threadIdx.x;
    for (int i = 0; i < 32; ++i) {
        int idx = i * 256 + tid;
        int r   = idx >> 10;
        int k   = idx & 1023;
        const float* ang = (r < 4) ? (ae + (r << 10)) : (ad + ((r - 4) << 10));
        float sv, cv;
        sincosf(ang[k], &sv, &cv);
        int t = k >> 6, j = k & 63;
        float2 e = make_float2(cv, sv);
        if (k == 1023) { s_aux[r] = e; e = make_float2(0.f, -1.f); }
        s_cs[(r * 64 + j) * 16 + t] = e;
    }
    __syncthreads();
    if (tid < NRINGS * 16) {
        int r = tid >> 4, t = tid & 15;
        float p = 1.f;
        for (int j = 0; j < 64; ++j) p *= -s_cs[(r * 64 + j) * 16 + t].y;
        s_A[tid] = p;
    }
    __syncthreads();

    const int lane      = tid & 63;
    const int g         = lane >> 4;
    const int t         = lane & 15;
    const int groupBase = lane & 48;
    const int row       = blockIdx.x * 16 + (tid >> 6) * 4 + g;

    const float* xr = x + (size_t)row * N_COLS + t * 64;
    float y[64];
    #pragma unroll
    for (int i = 0; i < 16; ++i) {
        float4 v = ((const float4*)xr)[i];
        y[4*i] = v.x; y[4*i+1] = v.y; y[4*i+2] = v.z; y[4*i+3] = v.w;
    }
    const float w   = 1.f / (1.f + expf(-hw[0]));
    const float omw = 1.f - w;

    for (int r = 0; r < NRINGS; ++r) {
        if (r == 4) {
            float4* ob = (float4*)(out + (size_t)row * N_COLS + t * 64);
            const float4* hp = (const float4*)(hs + t * 64);
            #pragma unroll
            for (int i = 0; i < 16; ++i) {
                float4 h = hp[i];
                float4 bn;
                bn.x = fmaf(omw, y[4*i+0], w * h.x);
                bn.y = fmaf(omw, y[4*i+1], w * h.y);
                bn.z = fmaf(omw, y[4*i+2], w * h.z);
                bn.w = fmaf(omw, y[4*i+3], w * h.w);
                ob[i] = bn;
                y[4*i+0] = bn.x; y[4*i+1] = bn.y; y[4*i+2] = bn.z; y[4*i+3] = bn.w;
            }
        }
        const float2* csr = s_cs + r * 64 * 16;
        const float2  cN  = s_aux[r];
        float y0 = __shfl(y[0],  groupBase);
        float yN = __shfl(y[63], groupBase + 15);
        float Cinit = cN.x * yN - cN.y * y0;
        float x0n   = fmaf(cN.y, yN, cN.x * y0);
        if (t == 0) y[0] = x0n;

        float carry = 0.f, ztmp = 0.f;
        #pragma unroll
        for (int j = 63; j >= 0; --j) {
            float2 cs = csr[j * 16 + t];
            float z   = fmaf(cs.y, y[j], cs.x * carry);
            carry     = fmaf(-cs.y, carry, cs.x * y[j]);
            if (j == 63) ztmp = z; else y[j + 1] = z;
        }
        float sa = s_A[r * 16 + t], sb = carry;
        #pragma unroll
        for (int d = 1; d < 16; d <<= 1) {
            float a2 = __shfl_down(sa, d);
            float b2 = __shfl_down(sb, d);
            if (t + d < 16) { sb = fmaf(sa, b2, sb); sa *= a2; }
        }
        float ea = __shfl_down(sa, 1);
        float eb = __shfl_down(sb, 1);
        float z0  = fmaf(sa, Cinit, sb);
        float Cin = (t == 15) ? Cinit : fmaf(ea, Cinit, eb);

        float P = 1.f;
        #pragma unroll
        for (int j = 63; j >= 0; --j) {
            float2 cs = csr[j * 16 + t];
            float f = cs.x * P;
            P = -cs.y * P;
            if (j == 63) ztmp = fmaf(f, Cin, ztmp);
            else         y[j + 1] = fmaf(f, Cin, y[j + 1]);
        }
        float up = __shfl_up(ztmp, 1);
        y[0] = (t == 0) ? z0 : up;
    }

    float4* oo = (float4*)(out + (size_t)B * N_COLS + (size_t)row * N_COLS + t * 64);
    #pragma unroll
    for (int i = 0; i < 16; ++i)
        oo[i] = make_float4(y[4*i], y[4*i+1], y[4*i+2], y[4*i+3]);
}

// ============================  launcher  ================================
extern "C" void kernel_launch(void* const* d_in, const int* in_sizes, int n_in,
                              void* d_out, int out_size, void* d_ws, size_t ws_size,
                              hipStream_t stream) {
    const float* x  = (const float*)d_in[0];
    const float* ae = (const float*)d_in[1];
    const float* ad = (const float*)d_in[2];
    const float* hw = (const float*)d_in[3];
    const float* hs = (const float*)d_in[4];
    float* out = (float*)d_out;
    const int B = in_sizes[0] / N_COLS;          // 8192

    if (ws_size >= WS_FLOATS * sizeof(float) && (B % (4 * QUADS_PER_BLOCK)) == 0) {
        hipLaunchKernelGGL(ced_setup, dim3(32), dim3(256), 0, stream,
                           ae, ad, (float*)d_ws);
        hipLaunchKernelGGL(ced_main, dim3(B / (4 * QUADS_PER_BLOCK)), dim3(256), 0, stream,
                           x, (const float*)d_ws, hw, hs, out, B);
    } else {
        hipLaunchKernelGGL(ced_fallback, dim3(B / 16), dim3(256), 0, stream,
                           x, ae, ad, hw, hs, out, B);
    }
}

// Round 7
// 126.093 us; speedup vs baseline: 1.1438x; 1.1438x over previous
//
#include <hip/hip_runtime.h>
#include <math.h>

#define N_COLS 1024
#define NRINGS 8

// ---- geometry: 64 lanes/row (full wave), 16 cols/thread, 4 rows/thread ----
#define TPR    64
#define CHUNK  16
#define QUADS_PER_BLOCK 4         // 256 threads / 64 lanes -> 4 quads -> 16 rows/block

// ws layout (floats) — identical to the R6/R8/R9-proven layout
#define F_OFF    16384            // CS  : 8 rings * 512 float4 = 16384 floats (64 KB)
#define A_OFF    24576            // F   : 8 rings * 256 float4 =  8192 floats (32 KB)
#define AUX_OFF  25088            // A   : 8 rings * 64 floats  =   512 floats
#define WS_FLOATS 25104           // AUX : 8 float2             =    16 floats

// =====================  setup: build angle tables  ======================
// grid = 32 blocks (4 per ring, 256 angles each). 1 sincos per thread.
//   CS  [(r*8 + jp)*64 + t] : float4 (c_j0,s_j0,c_j1,s_j1), k = t*16 + 2*jp
//   F   [(r*4 + q )*64 + t] : float4 f_j = c_j * prod_{l>j in chunk}(-s_l)
//   A   [r*64 + t]          : prod_j(-s_j) over chunk t
//   AUX [r]                 : real (c,s) at k=1023 (table entry doctored to
//                             (0,-1) = exact no-op chain step)
__global__ __launch_bounds__(256)
void ced_setup(const float* __restrict__ ae,
               const float* __restrict__ ad,
               float* __restrict__ ws)
{
    __shared__ float2 ls[256];
    const int r   = blockIdx.x >> 2;
    const int b   = blockIdx.x & 3;
    const int tid = threadIdx.x;
    const int k   = (b << 8) + tid;           // t = k>>4, j = k&15
    const float* ang = (r < 4) ? (ae + (r << 10)) : (ad + ((r - 4) << 10));

    float sv, cv;
    sincosf(ang[k], &sv, &cv);
    if (k == N_COLS - 1) {
        ((float2*)(ws + AUX_OFF))[r] = make_float2(cv, sv);
        cv = 0.f; sv = -1.f;                  // doctored: no-op step
    }
    ls[tid] = make_float2(cv, sv);
    __syncthreads();

    if (!(tid & 1)) {                         // paired (c,s) table
        float2 e0 = ls[tid], e1 = ls[tid + 1];
        int t  = k >> 4;
        int jp = (k & 15) >> 1;
        ((float4*)ws)[(r*8 + jp)*64 + t] = make_float4(e0.x, e0.y, e1.x, e1.y);
    }

    if (tid < 64) {                           // F and A via 2-round shfl product-scan
        const int lt = tid >> 2;              // local chunk 0..15
        const int q  = tid & 3;               // 4-element sub-segment 0..3
        const int t  = (b << 4) + lt;         // global chunk 0..63
        const int j0 = lt * CHUNK + 4 * q;
        float2 e0 = ls[j0], e1 = ls[j0+1], e2 = ls[j0+2], e3 = ls[j0+3];

        float f3 = e3.x;       float P = -e3.y;
        float f2 = e2.x * P;   P *= -e2.y;
        float f1 = e1.x * P;   P *= -e1.y;
        float f0 = e0.x * P;   P *= -e0.y;

        float ip = P;                         // inclusive suffix product over segments
        #pragma unroll
        for (int d = 1; d < 4; d <<= 1) {
            float tmp = __shfl_down(ip, d);
            if (q + d < 4) ip *= tmp;
        }
        float ex = __shfl_down(ip, 1);
        if (q == 3) ex = 1.f;
        f0 *= ex; f1 *= ex; f2 *= ex; f3 *= ex;

        ((float4*)(ws + F_OFF))[(r*4 + q)*64 + t] = make_float4(f0, f1, f2, f3);
        if (q == 0) ws[A_OFF + r*TPR + t] = ip;
    }
}

// =====================  main: fused enc->blend->dec  ====================
// R10 post-mortem: 4 rows + register-buffered tables (96 VGPR of csR/fvR)
// blew the (256,2) cap (=128; empirical cap = 256/min_waves_per_EU) ->
// ~80 MB spill, 64us. The 4-row direction was never tested spill-free.
// R11: 4 rows/thread CLEAN — tables read direct from global inside the
// ring loop (R9-proven, L1-resident), no register table buffers,
// launch_bounds(256,1) -> cap 256, demand ~150, zero spill. F/C model
// (R8=54, R9=44 -> F=20us, C=34us): T(4) = F/4 + C ~ 39us. 4 independent
// carry chains also raise VALU issue density at 2 waves/SIMD.
__global__ __launch_bounds__(256, 1)
void ced_main(const float* __restrict__ x,
              const float* __restrict__ ws,
              const float* __restrict__ hw,
              const float* __restrict__ hs,
              float* __restrict__ out, int B)
{
    const int tid  = threadIdx.x;
    const int t    = tid & 63;                       // chunk index within row
    const int quad = blockIdx.x * QUADS_PER_BLOCK + (tid >> 6);
    const size_t rowA = (size_t)(4 * quad) * N_COLS;
    const size_t rowB = rowA + N_COLS;
    const size_t rowC = rowB + N_COLS;
    const size_t rowD = rowC + N_COLS;

    const float4* CSg  = (const float4*)ws;
    const float4* Fg   = (const float4*)(ws + F_OFF);
    const float*  Ag   = ws + A_OFF;
    const float2* AUXg = (const float2*)(ws + AUX_OFF);

    // ---- load x (4 rows, 16 cols each) ----
    float ya[CHUNK], yb[CHUNK], yc[CHUNK], yd[CHUNK];
    {
        const float4* xa = (const float4*)(x + rowA + t * CHUNK);
        const float4* xb = (const float4*)(x + rowB + t * CHUNK);
        const float4* xc = (const float4*)(x + rowC + t * CHUNK);
        const float4* xd = (const float4*)(x + rowD + t * CHUNK);
        #pragma unroll
        for (int i = 0; i < 4; ++i) {
            float4 va = xa[i], vb = xb[i], vc = xc[i], vd = xd[i];
            ya[4*i] = va.x; ya[4*i+1] = va.y; ya[4*i+2] = va.z; ya[4*i+3] = va.w;
            yb[4*i] = vb.x; yb[4*i+1] = vb.y; yb[4*i+2] = vb.z; yb[4*i+3] = vb.w;
            yc[4*i] = vc.x; yc[4*i+1] = vc.y; yc[4*i+2] = vc.z; yc[4*i+3] = vc.w;
            yd[4*i] = vd.x; yd[4*i+1] = vd.y; yd[4*i+2] = vd.z; yd[4*i+3] = vd.w;
        }
    }

    const float w   = 1.f / (1.f + expf(-hw[0]));
    const float omw = 1.f - w;

    #pragma unroll 1
    for (int r = 0; r < NRINGS; ++r) {
        const float4* cs = CSg + r * 512;            // + jp*64 + t
        const float4* fp = Fg  + r * 256;            // + qi*64 + t
        const float  saI = Ag[r * TPR + t];
        const float2 cN  = AUXg[r];                  // uniform -> scalar load

        if (r == 4) {                 // bottleneck blend + output 0
            float4* oa = (float4*)(out + rowA + t * CHUNK);
            float4* ob = (float4*)(out + rowB + t * CHUNK);
            float4* oc = (float4*)(out + rowC + t * CHUNK);
            float4* od = (float4*)(out + rowD + t * CHUNK);
            const float4* hp = (const float4*)(hs + t * CHUNK);
            #pragma unroll
            for (int i = 0; i < 4; ++i) {
                float4 h = hp[i];
                float4 na, nb2, nc, nd;
                na.x  = fmaf(omw, ya[4*i+0], w * h.x);
                na.y  = fmaf(omw, ya[4*i+1], w * h.y);
                na.z  = fmaf(omw, ya[4*i+2], w * h.z);
                na.w  = fmaf(omw, ya[4*i+3], w * h.w);
                nb2.x = fmaf(omw, yb[4*i+0], w * h.x);
                nb2.y = fmaf(omw, yb[4*i+1], w * h.y);
                nb2.z = fmaf(omw, yb[4*i+2], w * h.z);
                nb2.w = fmaf(omw, yb[4*i+3], w * h.w);
                nc.x  = fmaf(omw, yc[4*i+0], w * h.x);
                nc.y  = fmaf(omw, yc[4*i+1], w * h.y);
                nc.z  = fmaf(omw, yc[4*i+2], w * h.z);
                nc.w  = fmaf(omw, yc[4*i+3], w * h.w);
                nd.x  = fmaf(omw, yd[4*i+0], w * h.x);
                nd.y  = fmaf(omw, yd[4*i+1], w * h.y);
                nd.z  = fmaf(omw, yd[4*i+2], w * h.z);
                nd.w  = fmaf(omw, yd[4*i+3], w * h.w);
                oa[i] = na; ob[i] = nb2; oc[i] = nc; od[i] = nd;
                ya[4*i+0] = na.x;  ya[4*i+1] = na.y;  ya[4*i+2] = na.z;  ya[4*i+3] = na.w;
                yb[4*i+0] = nb2.x; yb[4*i+1] = nb2.y; yb[4*i+2] = nb2.z; yb[4*i+3] = nb2.w;
                yc[4*i+0] = nc.x;  yc[4*i+1] = nc.y;  yc[4*i+2] = nc.z;  yc[4*i+3] = nc.w;
                yd[4*i+0] = nd.x;  yd[4*i+1] = nd.y;  yd[4*i+2] = nd.z;  yd[4*i+3] = nd.w;
            }
        }

        float y0a = __shfl(ya[0],       0);
        float yNa = __shfl(ya[CHUNK-1], 63);
        float y0b = __shfl(yb[0],       0);
        float yNb = __shfl(yb[CHUNK-1], 63);
        float y0c = __shfl(yc[0],       0);
        float yNc = __shfl(yc[CHUNK-1], 63);
        float y0d = __shfl(yd[0],       0);
        float yNd = __shfl(yd[CHUNK-1], 63);
        float CinitA = cN.x * yNa - cN.y * y0a;
        float CinitB = cN.x * yNb - cN.y * y0b;
        float CinitC = cN.x * yNc - cN.y * y0c;
        float CinitD = cN.x * yNd - cN.y * y0d;
        float x0nA   = fmaf(cN.y, yNa, cN.x * y0a);
        float x0nB   = fmaf(cN.y, yNb, cN.x * y0b);
        float x0nC   = fmaf(cN.y, yNc, cN.x * y0c);
        float x0nD   = fmaf(cN.y, yNd, cN.x * y0d);
        if (t == 0) { ya[0] = x0nA; yb[0] = x0nB; yc[0] = x0nC; yd[0] = x0nD; }

        // ---- pass 1: four independent local chains (carry_in = 0) ----
        float carA = 0.f, carB = 0.f, carC = 0.f, carD = 0.f;
        float ztA = 0.f, ztB = 0.f, ztC = 0.f, ztD = 0.f;
        #pragma unroll
        for (int jp = CHUNK/2 - 1; jp >= 0; --jp) {
            float4 cs4 = cs[jp * 64 + t];            // (c_j0,s_j0,c_j1,s_j1)
            const int j1 = 2*jp + 1;
            float z1a = fmaf(cs4.w, ya[j1], cs4.z * carA);
            float z1b = fmaf(cs4.w, yb[j1], cs4.z * carB);
            float z1c = fmaf(cs4.w, yc[j1], cs4.z * carC);
            float z1d = fmaf(cs4.w, yd[j1], cs4.z * carD);
            carA = fmaf(-cs4.w, carA, cs4.z * ya[j1]);
            carB = fmaf(-cs4.w, carB, cs4.z * yb[j1]);
            carC = fmaf(-cs4.w, carC, cs4.z * yc[j1]);
            carD = fmaf(-cs4.w, carD, cs4.z * yd[j1]);
            if (j1 == CHUNK - 1) { ztA = z1a; ztB = z1b; ztC = z1c; ztD = z1d; }
            else                 { ya[j1+1] = z1a; yb[j1+1] = z1b;
                                   yc[j1+1] = z1c; yd[j1+1] = z1d; }
            const int j0 = 2*jp;
            float z0a = fmaf(cs4.y, ya[j0], cs4.x * carA);
            float z0b = fmaf(cs4.y, yb[j0], cs4.x * carB);
            float z0c = fmaf(cs4.y, yc[j0], cs4.x * carC);
            float z0d = fmaf(cs4.y, yd[j0], cs4.x * carD);
            carA = fmaf(-cs4.y, carA, cs4.x * ya[j0]);
            carB = fmaf(-cs4.y, carB, cs4.x * yb[j0]);
            carC = fmaf(-cs4.y, carC, cs4.x * yc[j0]);
            carD = fmaf(-cs4.y, carD, cs4.x * yd[j0]);
            ya[j0+1] = z0a; yb[j0+1] = z0b; yc[j0+1] = z0c; yd[j0+1] = z0d;
        }

        // ---- affine suffix scan over 64 lanes (sa shared across 4 rows) ----
        float sa = saI, sbA = carA, sbB = carB, sbC = carC, sbD = carD;
        #pragma unroll
        for (int d = 1; d < TPR; d <<= 1) {
            float a2  = __shfl_down(sa,  d);
            float b2a = __shfl_down(sbA, d);
            float b2b = __shfl_down(sbB, d);
            float b2c = __shfl_down(sbC, d);
            float b2d = __shfl_down(sbD, d);
            if (t + d < TPR) {
                sbA = fmaf(sa, b2a, sbA);
                sbB = fmaf(sa, b2b, sbB);
                sbC = fmaf(sa, b2c, sbC);
                sbD = fmaf(sa, b2d, sbD);
                sa *= a2;
            }
        }
        float ea  = __shfl_down(sa,  1);
        float ebA = __shfl_down(sbA, 1);
        float ebB = __shfl_down(sbB, 1);
        float ebC = __shfl_down(sbC, 1);
        float ebD = __shfl_down(sbD, 1);
        float zfA = fmaf(sa, CinitA, sbA);           // lane0: final z[0]
        float zfB = fmaf(sa, CinitB, sbB);
        float zfC = fmaf(sa, CinitC, sbC);
        float zfD = fmaf(sa, CinitD, sbD);
        float CinA = (t == TPR - 1) ? CinitA : fmaf(ea, CinitA, ebA);
        float CinB = (t == TPR - 1) ? CinitB : fmaf(ea, CinitB, ebB);
        float CinC = (t == TPR - 1) ? CinitC : fmaf(ea, CinitC, ebC);
        float CinD = (t == TPR - 1) ? CinitD : fmaf(ea, CinitD, ebD);

        // ---- pass 2: independent fix-up with precomputed f ----
        #pragma unroll
        for (int qi = CHUNK/4 - 1; qi >= 0; --qi) {
            float4 f4 = fp[qi * 64 + t];
            const int j = 4*qi;
            if (j + 3 == CHUNK - 1) {
                ztA = fmaf(f4.w, CinA, ztA); ztB = fmaf(f4.w, CinB, ztB);
                ztC = fmaf(f4.w, CinC, ztC); ztD = fmaf(f4.w, CinD, ztD);
            } else {
                ya[j+4] = fmaf(f4.w, CinA, ya[j+4]); yb[j+4] = fmaf(f4.w, CinB, yb[j+4]);
                yc[j+4] = fmaf(f4.w, CinC, yc[j+4]); yd[j+4] = fmaf(f4.w, CinD, yd[j+4]);
            }
            ya[j+3] = fmaf(f4.z, CinA, ya[j+3]);  yb[j+3] = fmaf(f4.z, CinB, yb[j+3]);
            yc[j+3] = fmaf(f4.z, CinC, yc[j+3]);  yd[j+3] = fmaf(f4.z, CinD, yd[j+3]);
            ya[j+2] = fmaf(f4.y, CinA, ya[j+2]);  yb[j+2] = fmaf(f4.y, CinB, yb[j+2]);
            yc[j+2] = fmaf(f4.y, CinC, yc[j+2]);  yd[j+2] = fmaf(f4.y, CinD, yd[j+2]);
            ya[j+1] = fmaf(f4.x, CinA, ya[j+1]);  yb[j+1] = fmaf(f4.x, CinB, yb[j+1]);
            yc[j+1] = fmaf(f4.x, CinC, yc[j+1]);  yd[j+1] = fmaf(f4.x, CinD, yd[j+1]);
        }

        float upA = __shfl_up(ztA, 1);               // lane t-1's top -> slot 16t
        float upB = __shfl_up(ztB, 1);
        float upC = __shfl_up(ztC, 1);
        float upD = __shfl_up(ztD, 1);
        ya[0] = (t == 0) ? zfA : upA;
        yb[0] = (t == 0) ? zfB : upB;
        yc[0] = (t == 0) ? zfC : upC;
        yd[0] = (t == 0) ? zfD : upD;
    }

    float4* oa = (float4*)(out + (size_t)B * N_COLS + rowA + t * CHUNK);
    float4* ob = (float4*)(out + (size_t)B * N_COLS + rowB + t * CHUNK);
    float4* oc = (float4*)(out + (size_t)B * N_COLS + rowC + t * CHUNK);
    float4* od = (float4*)(out + (size_t)B * N_COLS + rowD + t * CHUNK);
    #pragma unroll
    for (int i = 0; i < 4; ++i) {
        oa[i] = make_float4(ya[4*i], ya[4*i+1], ya[4*i+2], ya[4*i+3]);
        ob[i] = make_float4(yb[4*i], yb[4*i+1], yb[4*i+2], yb[4*i+3]);
        oc[i] = make_float4(yc[4*i], yc[4*i+1], yc[4*i+2], yc[4*i+3]);
        od[i] = make_float4(yd[4*i], yd[4*i+1], yd[4*i+2], yd[4*i+3]);
    }
}

// ==================  fallback (self-contained, ws-free)  =================
__global__ __launch_bounds__(256, 2)
void ced_fallback(const float* __restrict__ x,
                  const float* __restrict__ ae,
                  const float* __restrict__ ad,
                  const float* __restrict__ hw,
                  const float* __restrict__ hs,
                  float* __restrict__ out, int B)
{
    __shared__ float2 s_cs[NRINGS * 64 * 16];
    __shared__ float  s_A [NRINGS * 16];
    __shared__ float2 s_aux[NRINGS];

    const int tid = threadIdx.x;
    for (int i = 0; i < 32; ++i) {
        int idx = i * 256 + tid;
        int r   = idx >> 10;
        int k   = idx & 1023;
        const float* ang = (r < 4) ? (ae + (r << 10)) : (ad + ((r - 4) << 10));
        float sv, cv;
        sincosf(ang[k], &sv, &cv);
        int t = k >> 6, j = k & 63;
        float2 e = make_float2(cv, sv);
        if (k == 1023) { s_aux[r] = e; e = make_float2(0.f, -1.f); }
        s_cs[(r * 64 + j) * 16 + t] = e;
    }
    __syncthreads();
    if (tid < NRINGS * 16) {
        int r = tid >> 4, t = tid & 15;
        float p = 1.f;
        for (int j = 0; j < 64; ++j) p *= -s_cs[(r * 64 + j) * 16 + t].y;
        s_A[tid] = p;
    }
    __syncthreads();

    const int lane      = tid & 63;
    const int g         = lane >> 4;
    const int t         = lane & 15;
    const int groupBase = lane & 48;
    const int row       = blockIdx.x * 16 + (tid >> 6) * 4 + g;

    const float* xr = x + (size_t)row * N_COLS + t * 64;
    float y[64];
    #pragma unroll
    for (int i = 0; i < 16; ++i) {
        float4 v = ((const float4*)xr)[i];
        y[4*i] = v.x; y[4*i+1] = v.y; y[4*i+2] = v.z; y[4*i+3] = v.w;
    }
    const float w   = 1.f / (1.f + expf(-hw[0]));
    const float omw = 1.f - w;

    for (int r = 0; r < NRINGS; ++r) {
        if (r == 4) {
            float4* ob = (float4*)(out + (size_t)row * N_COLS + t * 64);
            const float4* hp = (const float4*)(hs + t * 64);
            #pragma unroll
            for (int i = 0; i < 16; ++i) {
                float4 h = hp[i];
                float4 bn;
                bn.x = fmaf(omw, y[4*i+0], w * h.x);
                bn.y = fmaf(omw, y[4*i+1], w * h.y);
                bn.z = fmaf(omw, y[4*i+2], w * h.z);
                bn.w = fmaf(omw, y[4*i+3], w * h.w);
                ob[i] = bn;
                y[4*i+0] = bn.x; y[4*i+1] = bn.y; y[4*i+2] = bn.z; y[4*i+3] = bn.w;
            }
        }
        const float2* csr = s_cs + r * 64 * 16;
        const float2  cN  = s_aux[r];
        float y0 = __shfl(y[0],  groupBase);
        float yN = __shfl(y[63], groupBase + 15);
        float Cinit = cN.x * yN - cN.y * y0;
        float x0n   = fmaf(cN.y, yN, cN.x * y0);
        if (t == 0) y[0] = x0n;

        float carry = 0.f, ztmp = 0.f;
        #pragma unroll
        for (int j = 63; j >= 0; --j) {
            float2 cs = csr[j * 16 + t];
            float z   = fmaf(cs.y, y[j], cs.x * carry);
            carry     = fmaf(-cs.y, carry, cs.x * y[j]);
            if (j == 63) ztmp = z; else y[j + 1] = z;
        }
        float sa = s_A[r * 16 + t], sb = carry;
        #pragma unroll
        for (int d = 1; d < 16; d <<= 1) {
            float a2 = __shfl_down(sa, d);
            float b2 = __shfl_down(sb, d);
            if (t + d < 16) { sb = fmaf(sa, b2, sb); sa *= a2; }
        }
        float ea = __shfl_down(sa, 1);
        float eb = __shfl_down(sb, 1);
        float z0  = fmaf(sa, Cinit, sb);
        float Cin = (t == 15) ? Cinit : fmaf(ea, Cinit, eb);

        float P = 1.f;
        #pragma unroll
        for (int j = 63; j >= 0; --j) {
            float2 cs = csr[j * 16 + t];
            float f = cs.x * P;
            P = -cs.y * P;
            if (j == 63) ztmp = fmaf(f, Cin, ztmp);
            else         y[j + 1] = fmaf(f, Cin, y[j + 1]);
        }
        float up = __shfl_up(ztmp, 1);
        y[0] = (t == 0) ? z0 : up;
    }

    float4* oo = (float4*)(out + (size_t)B * N_COLS + (size_t)row * N_COLS + t * 64);
    #pragma unroll
    for (int i = 0; i < 16; ++i)
        oo[i] = make_float4(y[4*i], y[4*i+1], y[4*i+2], y[4*i+3]);
}

// ============================  launcher  ================================
extern "C" void kernel_launch(void* const* d_in, const int* in_sizes, int n_in,
                              void* d_out, int out_size, void* d_ws, size_t ws_size,
                              hipStream_t stream) {
    const float* x  = (const float*)d_in[0];
    const float* ae = (const float*)d_in[1];
    const float* ad = (const float*)d_in[2];
    const float* hw = (const float*)d_in[3];
    const float* hs = (const float*)d_in[4];
    float* out = (float*)d_out;
    const int B = in_sizes[0] / N_COLS;          // 8192

    if (ws_size >= WS_FLOATS * sizeof(float) && (B % (4 * QUADS_PER_BLOCK)) == 0) {
        hipLaunchKernelGGL(ced_setup, dim3(32), dim3(256), 0, stream,
                           ae, ad, (float*)d_ws);
        hipLaunchKernelGGL(ced_main, dim3(B / (4 * QUADS_PER_BLOCK)), dim3(256), 0, stream,
                           x, (const float*)d_ws, hw, hs, out, B);
    } else {
        hipLaunchKernelGGL(ced_fallback, dim3(B / 16), dim3(256), 0, stream,
                           x, ae, ad, hw, hs, out, B);
    }
}

// Round 8
// 123.128 us; speedup vs baseline: 1.1713x; 1.0241x over previous
//
#include <hip/hip_runtime.h>
#include <math.h>

#define N_COLS 1024
#define NRINGS 8

// ---- geometry: 64 lanes/row (full wave), 16 cols/thread, 2 rows/thread ----
#define TPR    64
#define CHUNK  16
#define PAIRS_PER_BLOCK 4         // 256 threads / 64 lanes-per-pair -> 8 rows/block

// ws layout (floats) — identical to the R6/R8/R9-proven layout
#define F_OFF    16384            // CS  : 8 rings * 512 float4 = 16384 floats (64 KB)
#define A_OFF    24576            // F   : 8 rings * 256 float4 =  8192 floats (32 KB)
#define AUX_OFF  25088            // A   : 8 rings * 64 floats  =   512 floats
#define WS_FLOATS 25104           // AUX : 8 float2             =    16 floats

// =====================  setup: build angle tables  ======================
// grid = 32 blocks (4 per ring, 256 angles each). 1 sincos per thread.
//   CS  [(r*8 + jp)*64 + t] : float4 (c_j0,s_j0,c_j1,s_j1), k = t*16 + 2*jp
//   F   [(r*4 + q )*64 + t] : float4 f_j = c_j * prod_{l>j in chunk}(-s_l)
//   A   [r*64 + t]          : prod_j(-s_j) over chunk t
//   AUX [r]                 : real (c,s) at k=1023 (table entry doctored to
//                             (0,-1) = exact no-op chain step)
__global__ __launch_bounds__(256)
void ced_setup(const float* __restrict__ ae,
               const float* __restrict__ ad,
               float* __restrict__ ws)
{
    __shared__ float2 ls[256];
    const int r   = blockIdx.x >> 2;
    const int b   = blockIdx.x & 3;
    const int tid = threadIdx.x;
    const int k   = (b << 8) + tid;           // t = k>>4, j = k&15
    const float* ang = (r < 4) ? (ae + (r << 10)) : (ad + ((r - 4) << 10));

    float sv, cv;
    sincosf(ang[k], &sv, &cv);
    if (k == N_COLS - 1) {
        ((float2*)(ws + AUX_OFF))[r] = make_float2(cv, sv);
        cv = 0.f; sv = -1.f;                  // doctored: no-op step
    }
    ls[tid] = make_float2(cv, sv);
    __syncthreads();

    if (!(tid & 1)) {                         // paired (c,s) table
        float2 e0 = ls[tid], e1 = ls[tid + 1];
        int t  = k >> 4;
        int jp = (k & 15) >> 1;
        ((float4*)ws)[(r*8 + jp)*64 + t] = make_float4(e0.x, e0.y, e1.x, e1.y);
    }

    if (tid < 64) {                           // F and A via 2-round shfl product-scan
        const int lt = tid >> 2;              // local chunk 0..15
        const int q  = tid & 3;               // 4-element sub-segment 0..3
        const int t  = (b << 4) + lt;         // global chunk 0..63
        const int j0 = lt * CHUNK + 4 * q;
        float2 e0 = ls[j0], e1 = ls[j0+1], e2 = ls[j0+2], e3 = ls[j0+3];

        float f3 = e3.x;       float P = -e3.y;
        float f2 = e2.x * P;   P *= -e2.y;
        float f1 = e1.x * P;   P *= -e1.y;
        float f0 = e0.x * P;   P *= -e0.y;

        float ip = P;                         // inclusive suffix product over segments
        #pragma unroll
        for (int d = 1; d < 4; d <<= 1) {
            float tmp = __shfl_down(ip, d);
            if (q + d < 4) ip *= tmp;
        }
        float ex = __shfl_down(ip, 1);
        if (q == 3) ex = 1.f;
        f0 *= ex; f1 *= ex; f2 *= ex; f3 *= ex;

        ((float4*)(ws + F_OFF))[(r*4 + q)*64 + t] = make_float4(f0, f1, f2, f3);
        if (q == 0) ws[A_OFF + r*TPR + t] = ip;
    }
}

// =====================  main: fused enc->blend->dec  ====================
// R11 post-mortem: runtime invariant to waves/CU (R8=54 @32, R9=44 @16,
// R11=46 @8) with NO pipe saturated -> wall = per-wave LATENCY; only
// shortening the per-ring serial chain helps. R9/R11's `#pragma unroll 1`
// forbade the compiler from hoisting ring r+1's 12 table loads above ring
// r's tail -> exposed L2 latency every ring (R10 proved prefetch works but
// manual 96-reg buffers blew the 128 cap). R12: straight-line all 8 rings
// (literal r, blend hoisted between ring 3 and 4), launch_bounds(256,1)
// so the allocator hoists loads freely without a cap spill. 2-row R9
// geometry (best measured, smallest y-state).
#define RING_STEP(RR)                                                          \
{                                                                              \
    const float4* cs = CSg + (RR) * 512;                                       \
    const float4* fp = Fg  + (RR) * 256;                                       \
    const float  saI = Ag[(RR) * TPR + t];                                     \
    const float2 cN  = AUXg[(RR)];                                             \
    float y0a = __shfl(ya[0],       0);                                        \
    float yNa = __shfl(ya[CHUNK-1], 63);                                       \
    float y0b = __shfl(yb[0],       0);                                        \
    float yNb = __shfl(yb[CHUNK-1], 63);                                       \
    float CinitA = cN.x * yNa - cN.y * y0a;                                    \
    float CinitB = cN.x * yNb - cN.y * y0b;                                    \
    float x0nA   = fmaf(cN.y, yNa, cN.x * y0a);                                \
    float x0nB   = fmaf(cN.y, yNb, cN.x * y0b);                                \
    if (t == 0) { ya[0] = x0nA; yb[0] = x0nB; }                                \
    float carA = 0.f, carB = 0.f, ztA = 0.f, ztB = 0.f;                        \
    _Pragma("unroll")                                                          \
    for (int jp = CHUNK/2 - 1; jp >= 0; --jp) {                                \
        float4 cs4 = cs[jp * 64 + t];                                          \
        const int j1 = 2*jp + 1;                                               \
        float z1a = fmaf(cs4.w, ya[j1], cs4.z * carA);                         \
        float z1b = fmaf(cs4.w, yb[j1], cs4.z * carB);                         \
        carA = fmaf(-cs4.w, carA, cs4.z * ya[j1]);                             \
        carB = fmaf(-cs4.w, carB, cs4.z * yb[j1]);                             \
        if (j1 == CHUNK - 1) { ztA = z1a; ztB = z1b; }                         \
        else                 { ya[j1+1] = z1a; yb[j1+1] = z1b; }               \
        const int j0 = 2*jp;                                                   \
        float z0a = fmaf(cs4.y, ya[j0], cs4.x * carA);                         \
        float z0b = fmaf(cs4.y, yb[j0], cs4.x * carB);                         \
        carA = fmaf(-cs4.y, carA, cs4.x * ya[j0]);                             \
        carB = fmaf(-cs4.y, carB, cs4.x * yb[j0]);                             \
        ya[j0+1] = z0a; yb[j0+1] = z0b;                                        \
    }                                                                          \
    float sa = saI, sbA = carA, sbB = carB;                                    \
    _Pragma("unroll")                                                          \
    for (int d = 1; d < TPR; d <<= 1) {                                        \
        float a2  = __shfl_down(sa,  d);                                       \
        float b2a = __shfl_down(sbA, d);                                       \
        float b2b = __shfl_down(sbB, d);                                       \
        if (t + d < TPR) {                                                     \
            sbA = fmaf(sa, b2a, sbA);                                          \
            sbB = fmaf(sa, b2b, sbB);                                          \
            sa *= a2;                                                          \
        }                                                                      \
    }                                                                          \
    float ea  = __shfl_down(sa,  1);                                           \
    float ebA = __shfl_down(sbA, 1);                                           \
    float ebB = __shfl_down(sbB, 1);                                           \
    float zfA = fmaf(sa, CinitA, sbA);                                         \
    float zfB = fmaf(sa, CinitB, sbB);                                         \
    float CinA = (t == TPR - 1) ? CinitA : fmaf(ea, CinitA, ebA);              \
    float CinB = (t == TPR - 1) ? CinitB : fmaf(ea, CinitB, ebB);              \
    _Pragma("unroll")                                                          \
    for (int qi = CHUNK/4 - 1; qi >= 0; --qi) {                                \
        float4 f4 = fp[qi * 64 + t];                                           \
        const int j = 4*qi;                                                    \
        if (j + 3 == CHUNK - 1) { ztA = fmaf(f4.w, CinA, ztA);                 \
                                  ztB = fmaf(f4.w, CinB, ztB); }               \
        else                    { ya[j+4] = fmaf(f4.w, CinA, ya[j+4]);         \
                                  yb[j+4] = fmaf(f4.w, CinB, yb[j+4]); }       \
        ya[j+3] = fmaf(f4.z, CinA, ya[j+3]);  yb[j+3] = fmaf(f4.z, CinB, yb[j+3]); \
        ya[j+2] = fmaf(f4.y, CinA, ya[j+2]);  yb[j+2] = fmaf(f4.y, CinB, yb[j+2]); \
        ya[j+1] = fmaf(f4.x, CinA, ya[j+1]);  yb[j+1] = fmaf(f4.x, CinB, yb[j+1]); \
    }                                                                          \
    float upA = __shfl_up(ztA, 1);                                             \
    float upB = __shfl_up(ztB, 1);                                             \
    ya[0] = (t == 0) ? zfA : upA;                                              \
    yb[0] = (t == 0) ? zfB : upB;                                              \
}

__global__ __launch_bounds__(256, 1)
void ced_main(const float* __restrict__ x,
              const float* __restrict__ ws,
              const float* __restrict__ hw,
              const float* __restrict__ hs,
              float* __restrict__ out, int B)
{
    const int tid = threadIdx.x;
    const int t   = tid & 63;                        // chunk index within row
    const int pairRow = blockIdx.x * PAIRS_PER_BLOCK + (tid >> 6);
    const size_t rowA = (size_t)(2 * pairRow) * N_COLS;
    const size_t rowB = rowA + N_COLS;

    const float4* CSg  = (const float4*)ws;
    const float4* Fg   = (const float4*)(ws + F_OFF);
    const float*  Ag   = ws + A_OFF;
    const float2* AUXg = (const float2*)(ws + AUX_OFF);

    // ---- load x (2 rows, 16 cols each) ----
    float ya[CHUNK], yb[CHUNK];
    {
        const float4* xa = (const float4*)(x + rowA + t * CHUNK);
        const float4* xb = (const float4*)(x + rowB + t * CHUNK);
        #pragma unroll
        for (int i = 0; i < 4; ++i) {
            float4 va = xa[i], vb = xb[i];
            ya[4*i] = va.x; ya[4*i+1] = va.y; ya[4*i+2] = va.z; ya[4*i+3] = va.w;
            yb[4*i] = vb.x; yb[4*i+1] = vb.y; yb[4*i+2] = vb.z; yb[4*i+3] = vb.w;
        }
    }

    const float w   = 1.f / (1.f + expf(-hw[0]));
    const float omw = 1.f - w;

    // ---- encoder rings 0..3 (straight-line: loads hoistable across rings) --
    RING_STEP(0)
    RING_STEP(1)
    RING_STEP(2)
    RING_STEP(3)

    // ---- bottleneck blend + output 0 ----
    {
        float4* oa = (float4*)(out + rowA + t * CHUNK);
        float4* ob = (float4*)(out + rowB + t * CHUNK);
        const float4* hp = (const float4*)(hs + t * CHUNK);
        #pragma unroll
        for (int i = 0; i < 4; ++i) {
            float4 h = hp[i];
            float4 na, nb2;
            na.x  = fmaf(omw, ya[4*i+0], w * h.x);
            na.y  = fmaf(omw, ya[4*i+1], w * h.y);
            na.z  = fmaf(omw, ya[4*i+2], w * h.z);
            na.w  = fmaf(omw, ya[4*i+3], w * h.w);
            nb2.x = fmaf(omw, yb[4*i+0], w * h.x);
            nb2.y = fmaf(omw, yb[4*i+1], w * h.y);
            nb2.z = fmaf(omw, yb[4*i+2], w * h.z);
            nb2.w = fmaf(omw, yb[4*i+3], w * h.w);
            oa[i] = na; ob[i] = nb2;
            ya[4*i+0] = na.x;  ya[4*i+1] = na.y;  ya[4*i+2] = na.z;  ya[4*i+3] = na.w;
            yb[4*i+0] = nb2.x; yb[4*i+1] = nb2.y; yb[4*i+2] = nb2.z; yb[4*i+3] = nb2.w;
        }
    }

    // ---- decoder rings 4..7 ----
    RING_STEP(4)
    RING_STEP(5)
    RING_STEP(6)
    RING_STEP(7)

    float4* oa = (float4*)(out + (size_t)B * N_COLS + rowA + t * CHUNK);
    float4* ob = (float4*)(out + (size_t)B * N_COLS + rowB + t * CHUNK);
    #pragma unroll
    for (int i = 0; i < 4; ++i) {
        oa[i] = make_float4(ya[4*i], ya[4*i+1], ya[4*i+2], ya[4*i+3]);
        ob[i] = make_float4(yb[4*i], yb[4*i+1], yb[4*i+2], yb[4*i+3]);
    }
}

// ==================  fallback (self-contained, ws-free)  =================
__global__ __launch_bounds__(256, 2)
void ced_fallback(const float* __restrict__ x,
                  const float* __restrict__ ae,
                  const float* __restrict__ ad,
                  const float* __restrict__ hw,
                  const float* __restrict__ hs,
                  float* __restrict__ out, int B)
{
    __shared__ float2 s_cs[NRINGS * 64 * 16];
    __shared__ float  s_A [NRINGS * 16];
    __shared__ float2 s_aux[NRINGS];

    const int tid = threadIdx.x;
    for (int i = 0; i < 32; ++i) {
        int idx = i * 256 + tid;
        int r   = idx >> 10;
        int k   = idx & 1023;
        const float* ang = (r < 4) ? (ae + (r << 10)) : (ad + ((r - 4) << 10));
        float sv, cv;
        sincosf(ang[k], &sv, &cv);
        int t = k >> 6, j = k & 63;
        float2 e = make_float2(cv, sv);
        if (k == 1023) { s_aux[r] = e; e = make_float2(0.f, -1.f); }
        s_cs[(r * 64 + j) * 16 + t] = e;
    }
    __syncthreads();
    if (tid < NRINGS * 16) {
        int r = tid >> 4, t = tid & 15;
        float p = 1.f;
        for (int j = 0; j < 64; ++j) p *= -s_cs[(r * 64 + j) * 16 + t].y;
        s_A[tid] = p;
    }
    __syncthreads();

    const int lane      = tid & 63;
    const int g         = lane >> 4;
    const int t         = lane & 15;
    const int groupBase = lane & 48;
    const int row       = blockIdx.x * 16 + (tid >> 6) * 4 + g;

    const float* xr = x + (size_t)row * N_COLS + t * 64;
    float y[64];
    #pragma unroll
    for (int i = 0; i < 16; ++i) {
        float4 v = ((const float4*)xr)[i];
        y[4*i] = v.x; y[4*i+1] = v.y; y[4*i+2] = v.z; y[4*i+3] = v.w;
    }
    const float w   = 1.f / (1.f + expf(-hw[0]));
    const float omw = 1.f - w;

    for (int r = 0; r < NRINGS; ++r) {
        if (r == 4) {
            float4* ob = (float4*)(out + (size_t)row * N_COLS + t * 64);
            const float4* hp = (const float4*)(hs + t * 64);
            #pragma unroll
            for (int i = 0; i < 16; ++i) {
                float4 h = hp[i];
                float4 bn;
                bn.x = fmaf(omw, y[4*i+0], w * h.x);
                bn.y = fmaf(omw, y[4*i+1], w * h.y);
                bn.z = fmaf(omw, y[4*i+2], w * h.z);
                bn.w = fmaf(omw, y[4*i+3], w * h.w);
                ob[i] = bn;
                y[4*i+0] = bn.x; y[4*i+1] = bn.y; y[4*i+2] = bn.z; y[4*i+3] = bn.w;
            }
        }
        const float2* csr = s_cs + r * 64 * 16;
        const float2  cN  = s_aux[r];
        float y0 = __shfl(y[0],  groupBase);
        float yN = __shfl(y[63], groupBase + 15);
        float Cinit = cN.x * yN - cN.y * y0;
        float x0n   = fmaf(cN.y, yN, cN.x * y0);
        if (t == 0) y[0] = x0n;

        float carry = 0.f, ztmp = 0.f;
        #pragma unroll
        for (int j = 63; j >= 0; --j) {
            float2 cs = csr[j * 16 + t];
            float z   = fmaf(cs.y, y[j], cs.x * carry);
            carry     = fmaf(-cs.y, carry, cs.x * y[j]);
            if (j == 63) ztmp = z; else y[j + 1] = z;
        }
        float sa = s_A[r * 16 + t], sb = carry;
        #pragma unroll
        for (int d = 1; d < 16; d <<= 1) {
            float a2 = __shfl_down(sa, d);
            float b2 = __shfl_down(sb, d);
            if (t + d < 16) { sb = fmaf(sa, b2, sb); sa *= a2; }
        }
        float ea = __shfl_down(sa, 1);
        float eb = __shfl_down(sb, 1);
        float z0  = fmaf(sa, Cinit, sb);
        float Cin = (t == 15) ? Cinit : fmaf(ea, Cinit, eb);

        float P = 1.f;
        #pragma unroll
        for (int j = 63; j >= 0; --j) {
            float2 cs = csr[j * 16 + t];
            float f = cs.x * P;
            P = -cs.y * P;
            if (j == 63) ztmp = fmaf(f, Cin, ztmp);
            else         y[j + 1] = fmaf(f, Cin, y[j + 1]);
        }
        float up = __shfl_up(ztmp, 1);
        y[0] = (t == 0) ? z0 : up;
    }

    float4* oo = (float4*)(out + (size_t)B * N_COLS + (size_t)row * N_COLS + t * 64);
    #pragma unroll
    for (int i = 0; i < 16; ++i)
        oo[i] = make_float4(y[4*i], y[4*i+1], y[4*i+2], y[4*i+3]);
}

// ============================  launcher  ================================
extern "C" void kernel_launch(void* const* d_in, const int* in_sizes, int n_in,
                              void* d_out, int out_size, void* d_ws, size_t ws_size,
                              hipStream_t stream) {
    const float* x  = (const float*)d_in[0];
    const float* ae = (const float*)d_in[1];
    const float* ad = (const float*)d_in[2];
    const float* hw = (const float*)d_in[3];
    const float* hs = (const float*)d_in[4];
    float* out = (float*)d_out;
    const int B = in_sizes[0] / N_COLS;          // 8192

    if (ws_size >= WS_FLOATS * sizeof(float) && (B % (2 * PAIRS_PER_BLOCK)) == 0) {
        hipLaunchKernelGGL(ced_setup, dim3(32), dim3(256), 0, stream,
                           ae, ad, (float*)d_ws);
        hipLaunchKernelGGL(ced_main, dim3(B / (2 * PAIRS_PER_BLOCK)), dim3(256), 0, stream,
                           x, (const float*)d_ws, hw, hs, out, B);
    } else {
        hipLaunchKernelGGL(ced_fallback, dim3(B / 16), dim3(256), 0, stream,
                           x, ae, ad, hw, hs, out, B);
    }
}